// Round 2
// baseline (694.965 us; speedup 1.0000x reference)
//
#include <hip/hip_runtime.h>

typedef __bf16 bf16;
typedef bf16 bf16x8 __attribute__((ext_vector_type(8)));
typedef float f32x4 __attribute__((ext_vector_type(4)));

#define MFMA(a, b, c) __builtin_amdgcn_mfma_f32_16x16x32_bf16(a, b, c, 0, 0, 0)

// row r in window order (win = r/64 = b*256 + wh*16 + ww, n = r%64) -> token index
// in original (B, H*W) layout, accounting for the cyclic shift by 4.
static __device__ __forceinline__ int perm_token(int r) {
    int b  = r >> 14;
    int wl = (r >> 6) & 255;
    int n  = r & 63;
    int h  = (((wl >> 4) << 3) + (n >> 3) + 4) & 127;
    int w  = (((wl & 15) << 3) + (n & 7) + 4) & 127;
    return (b << 14) + (h << 7) + w;
}

// MODE 0: LN1, src = fp32 x, gather rows through perm_token (roll + window partition)
// MODE 1: LN2, src = fp32 x2, identity row mapping.  Output bf16.
template<int MODE>
__global__ __launch_bounds__(256) void ln_kernel(const float* __restrict__ src,
        const float* __restrict__ w, const float* __restrict__ bvec, bf16* __restrict__ dst) {
    int row  = blockIdx.x * 4 + (threadIdx.x >> 6);
    int lane = threadIdx.x & 63;
    const float* s;
    if constexpr (MODE == 0) s = src + (size_t)perm_token(row) * 192;
    else                     s = src + (size_t)row * 192;
    float v0 = s[lane], v1 = s[lane + 64], v2 = s[lane + 128];
    float sm = v0 + v1 + v2;
    float sq = v0 * v0 + v1 * v1 + v2 * v2;
    #pragma unroll
    for (int m = 1; m < 64; m <<= 1) { sm += __shfl_xor(sm, m); sq += __shfl_xor(sq, m); }
    float mu = sm * (1.0f / 192.0f);
    float rs = rsqrtf(sq * (1.0f / 192.0f) - mu * mu + 1e-5f);
    bf16* o = dst + (size_t)row * 192;
    o[lane]       = (bf16)((v0 - mu) * rs * w[lane]       + bvec[lane]);
    o[lane + 64]  = (bf16)((v1 - mu) * rs * w[lane + 64]  + bvec[lane + 64]);
    o[lane + 128] = (bf16)((v2 - mu) * rs * w[lane + 128] + bvec[lane + 128]);
}

// fp32 [K,N] -> bf16 [N,K]
__global__ __launch_bounds__(256) void transpose_k(const float* __restrict__ src,
        bf16* __restrict__ dst, int K, int N) {
    int idx = blockIdx.x * 256 + threadIdx.x;
    if (idx < K * N) {
        int k = idx / N, n = idx % N;
        dst[(size_t)n * K + k] = (bf16)src[idx];
    }
}

// C[M,N] = A[M,K] * Bt[N,K]^T, bf16 MFMA, fp32 accum. EPI:
// 0 = bias -> bf16
// 1 = bias + exact GELU -> bf16
// 2 = proj: bias + window-reverse/roll + residual(fp32 x) -> fp32 x2[token]
// 3 = out:  bias + residual(fp32 x2) -> fp32
template<int EPI>
__global__ __launch_bounds__(256) void gemm_k(const bf16* __restrict__ A, const bf16* __restrict__ Bt,
        const float* __restrict__ bias, void* __restrict__ Cout, const float* __restrict__ res,
        int M, int N, int K) {
    __shared__ bf16 As[64][72];
    __shared__ bf16 Bs[64][72];
    const int tid  = threadIdx.x;
    const int lane = tid & 63;
    const int wm   = tid >> 7;          // 0..1
    const int wn   = (tid >> 6) & 1;    // 0..1
    const size_t brow = (size_t)blockIdx.x * 64;
    const size_t bcol = (size_t)blockIdx.y * 64;
    const int sr = tid >> 2;            // staging row 0..63
    const int sc = (tid & 3) << 4;      // staging col 0,16,32,48
    const int lr = lane & 15;
    const int lk = (lane >> 4) << 3;

    f32x4 acc[2][2] = {};
    for (int k0 = 0; k0 < K; k0 += 64) {
        __syncthreads();
        const bf16* ga = A  + (brow + sr) * K + k0 + sc;
        const bf16* gb = Bt + (bcol + sr) * K + k0 + sc;
        *(bf16x8*)&As[sr][sc]     = *(const bf16x8*)ga;
        *(bf16x8*)&As[sr][sc + 8] = *(const bf16x8*)(ga + 8);
        *(bf16x8*)&Bs[sr][sc]     = *(const bf16x8*)gb;
        *(bf16x8*)&Bs[sr][sc + 8] = *(const bf16x8*)(gb + 8);
        __syncthreads();
        #pragma unroll
        for (int kk = 0; kk < 64; kk += 32) {
            bf16x8 a0 = *(const bf16x8*)&As[wm * 32 + lr][kk + lk];
            bf16x8 a1 = *(const bf16x8*)&As[wm * 32 + 16 + lr][kk + lk];
            bf16x8 b0 = *(const bf16x8*)&Bs[wn * 32 + lr][kk + lk];
            bf16x8 b1 = *(const bf16x8*)&Bs[wn * 32 + 16 + lr][kk + lk];
            acc[0][0] = MFMA(a0, b0, acc[0][0]);
            acc[0][1] = MFMA(a0, b1, acc[0][1]);
            acc[1][0] = MFMA(a1, b0, acc[1][0]);
            acc[1][1] = MFMA(a1, b1, acc[1][1]);
        }
    }
    const int fr = (lane >> 4) << 2;
    #pragma unroll
    for (int mi = 0; mi < 2; ++mi)
    #pragma unroll
    for (int ni = 0; ni < 2; ++ni)
    #pragma unroll
    for (int rr = 0; rr < 4; ++rr) {
        size_t row = brow + wm * 32 + mi * 16 + fr + rr;
        size_t col = bcol + wn * 32 + ni * 16 + lr;
        float v = acc[mi][ni][rr] + bias[col];
        if constexpr (EPI == 0) {
            ((bf16*)Cout)[row * N + col] = (bf16)v;
        } else if constexpr (EPI == 1) {
            ((bf16*)Cout)[row * N + col] = (bf16)(0.5f * v * (1.0f + erff(v * 0.70710678118f)));
        } else if constexpr (EPI == 2) {
            size_t t = (size_t)perm_token((int)row);
            ((float*)Cout)[t * 192 + col] = v + res[t * 192 + col];
        } else {
            ((float*)Cout)[row * 192 + col] = v + res[row * 192 + col];
        }
    }
}

// One block = (window, 3 heads). One wave per head. N=64 tokens, hd=32.
__global__ __launch_bounds__(192) void attn_k(const bf16* __restrict__ qkv,
        const float* __restrict__ rpb, bf16* __restrict__ out) {
    __shared__ bf16 Vt[96][72];          // V transposed: Vt[d_local][m]
    __shared__ bf16 P[3][64][72];        // probabilities per local head
    __shared__ float rpbs[1350];         // 225 * 6
    const int tid = threadIdx.x;
    const int win = blockIdx.x;
    const int hb  = blockIdx.y;          // head-block (0: heads 0-2, 1: heads 3-5)
    const size_t base = (size_t)win * 64 * 576;

    for (int i = tid; i < 1350; i += 192) rpbs[i] = rpb[i];
    #pragma unroll
    for (int it = 0; it < 4; ++it) {
        int idx = it * 192 + tid;        // 0..767 = 64 rows * 12 chunks
        int m = idx / 12, c8 = idx % 12;
        bf16x8 v = *(const bf16x8*)(qkv + base + (size_t)m * 576 + 384 + hb * 96 + c8 * 8);
        #pragma unroll
        for (int j = 0; j < 8; ++j) Vt[c8 * 8 + j][m] = v[j];
    }
    __syncthreads();

    const int lh   = tid >> 6;
    const int h    = hb * 3 + lh;
    const int lane = tid & 63;
    const int lr = lane & 15;
    const int lg = lane >> 4;
    const int lk = lg << 3;

    bf16x8 qf[4], kf[4];
    #pragma unroll
    for (int mi = 0; mi < 4; ++mi) {
        const bf16* p = qkv + base + (size_t)(mi * 16 + lr) * 576 + h * 32 + lk;
        qf[mi] = *(const bf16x8*)p;
        kf[mi] = *(const bf16x8*)(p + 192);
    }
    f32x4 S[4][4] = {};
    #pragma unroll
    for (int mi = 0; mi < 4; ++mi)
    #pragma unroll
    for (int ni = 0; ni < 4; ++ni)
        S[mi][ni] = MFMA(qf[mi], kf[ni], S[mi][ni]);

    const int wl = win & 255, wh = wl >> 4, ww = wl & 15;
    const bool edge = (wh == 15) || (ww == 15);
    const float scale = 0.17677669529663687f;   // 1/sqrt(32)
    #pragma unroll
    for (int mi = 0; mi < 4; ++mi)
    #pragma unroll
    for (int rr = 0; rr < 4; ++rr) {
        int row = mi * 16 + lg * 4 + rr;
        int ry = row >> 3, rx = row & 7;
        int labr = ((wh == 15) ? ((ry >= 4) ? 2 : 1) : 0) * 3
                 + ((ww == 15) ? ((rx >= 4) ? 2 : 1) : 0);
        float v[4];
        float mx = -1e30f;
        #pragma unroll
        for (int ni = 0; ni < 4; ++ni) {
            int col = ni * 16 + lr;
            int cy = col >> 3, cx = col & 7;
            float s = S[mi][ni][rr] * scale
                    + rpbs[((ry - cy + 7) * 15 + (rx - cx + 7)) * 6 + h];
            if (edge) {
                int labc = ((wh == 15) ? ((cy >= 4) ? 2 : 1) : 0) * 3
                         + ((ww == 15) ? ((cx >= 4) ? 2 : 1) : 0);
                if (labc != labr) s -= 100.0f;
            }
            v[ni] = s;
            mx = fmaxf(mx, s);
        }
        #pragma unroll
        for (int m = 1; m < 16; m <<= 1) mx = fmaxf(mx, __shfl_xor(mx, m));
        float sum = 0.0f;
        #pragma unroll
        for (int ni = 0; ni < 4; ++ni) { v[ni] = __expf(v[ni] - mx); sum += v[ni]; }
        #pragma unroll
        for (int m = 1; m < 16; m <<= 1) sum += __shfl_xor(sum, m);
        float inv = 1.0f / sum;
        #pragma unroll
        for (int ni = 0; ni < 4; ++ni) P[lh][row][ni * 16 + lr] = (bf16)(v[ni] * inv);
    }
    __syncthreads();

    f32x4 O[4][2] = {};
    #pragma unroll
    for (int kk = 0; kk < 64; kk += 32) {
        bf16x8 pf[4], vf[2];
        #pragma unroll
        for (int mi = 0; mi < 4; ++mi) pf[mi] = *(const bf16x8*)&P[lh][mi * 16 + lr][kk + lk];
        #pragma unroll
        for (int nj = 0; nj < 2; ++nj) vf[nj] = *(const bf16x8*)&Vt[lh * 32 + nj * 16 + lr][kk + lk];
        #pragma unroll
        for (int mi = 0; mi < 4; ++mi)
        #pragma unroll
        for (int nj = 0; nj < 2; ++nj)
            O[mi][nj] = MFMA(pf[mi], vf[nj], O[mi][nj]);
    }
    #pragma unroll
    for (int mi = 0; mi < 4; ++mi)
    #pragma unroll
    for (int nj = 0; nj < 2; ++nj)
    #pragma unroll
    for (int rr = 0; rr < 4; ++rr) {
        int row = mi * 16 + lg * 4 + rr;
        out[((size_t)win * 64 + row) * 192 + h * 32 + nj * 16 + lr] = (bf16)O[mi][nj][rr];
    }
}

extern "C" void kernel_launch(void* const* d_in, const int* in_sizes, int n_in,
                              void* d_out, int out_size, void* d_ws, size_t ws_size,
                              hipStream_t stream) {
    (void)in_sizes; (void)n_in; (void)out_size; (void)ws_size;
    const float* x      = (const float*)d_in[0];
    const float* qkv_w  = (const float*)d_in[3];
    const float* qkv_b  = (const float*)d_in[4];
    const float* proj_w = (const float*)d_in[5];
    const float* proj_b = (const float*)d_in[6];
    const float* rpb    = (const float*)d_in[7];
    const float* n1w    = (const float*)d_in[8];
    const float* n1b    = (const float*)d_in[9];
    const float* n2w    = (const float*)d_in[10];
    const float* n2b    = (const float*)d_in[11];
    const float* w1     = (const float*)d_in[12];
    const float* b1     = (const float*)d_in[13];
    const float* w2     = (const float*)d_in[14];
    const float* b2     = (const float*)d_in[15];
    float* out          = (float*)d_out;

    // workspace layout (bytes), peak ~252.5 MB:
    //   [0,          50331648)  windows bf16            -> reused as h2 (bf16)
    //   [50331648,  201326592)  qkv bf16 (151 MB)       -> reused as x2 fp32 (100 MB)
    //   [201326592, 251658240)  attn_out bf16 (50 MB)   -> reused as MLP hidden chunk bf16
    //   [251658240, +884736)    transposed bf16 weights
    char* ws = (char*)d_ws;
    bf16*  windows = (bf16*)(ws);
    bf16*  qkv     = (bf16*)(ws + 50331648UL);
    bf16*  attn_o  = (bf16*)(ws + 201326592UL);
    float* x2      = (float*)(ws + 50331648UL);
    bf16*  h2      = (bf16*)(ws);
    bf16*  hidden  = (bf16*)(ws + 201326592UL);
    bf16*  qkvwT   = (bf16*)(ws + 251658240UL);
    bf16*  projwT  = qkvwT + 110592;
    bf16*  w1T     = projwT + 36864;
    bf16*  w2T     = w1T + 147456;

    transpose_k<<<dim3((110592 + 255) / 256), 256, 0, stream>>>(qkv_w, qkvwT, 192, 576);
    transpose_k<<<dim3((36864 + 255) / 256), 256, 0, stream>>>(proj_w, projwT, 192, 192);
    transpose_k<<<dim3((147456 + 255) / 256), 256, 0, stream>>>(w1, w1T, 192, 768);
    transpose_k<<<dim3((147456 + 255) / 256), 256, 0, stream>>>(w2, w2T, 768, 192);

    ln_kernel<0><<<dim3(32768), 256, 0, stream>>>(x, n1w, n1b, windows);
    gemm_k<0><<<dim3(2048, 9), 256, 0, stream>>>(windows, qkvwT, qkv_b, qkv, nullptr, 131072, 576, 192);
    attn_k<<<dim3(2048, 2), 192, 0, stream>>>(qkv, rpb, attn_o);
    gemm_k<2><<<dim3(2048, 3), 256, 0, stream>>>(attn_o, projwT, proj_b, x2, x, 131072, 192, 192);
    ln_kernel<1><<<dim3(32768), 256, 0, stream>>>(x2, n2w, n2b, h2);
    // MLP in 4 row-chunks of 32768 so the hidden buffer fits in the dead attn_o region.
    for (int c = 0; c < 4; ++c) {
        size_t off = (size_t)c * 32768 * 192;
        gemm_k<1><<<dim3(512, 12), 256, 0, stream>>>(h2 + off, w1T, b1, hidden, nullptr, 32768, 768, 192);
        gemm_k<3><<<dim3(512, 3), 256, 0, stream>>>(hidden, w2T, b2, out + off, x2 + off, 32768, 192, 768);
    }
}